// Round 5
// baseline (408.435 us; speedup 1.0000x reference)
//
#include <hip/hip_runtime.h>
#include <hip/hip_cooperative_groups.h>
#include <math.h>

namespace cg = cooperative_groups;

#define HID 2048
#define KQ (HID / 4)
#define MAXLEN 128
#define VOCAB 32000
#define NBLK 512
#define NTHR 256

__device__ __forceinline__ float wave_sum(float v) {
    #pragma unroll
    for (int m = 1; m < 64; m <<= 1) v += __shfl_xor(v, m, 64);
    return v;
}

__device__ __forceinline__ float dot4(float4 a, float4 b) {
    return a.x * b.x + a.y * b.y + a.z * b.z + a.w * b.w;
}

// ======================= fused cooperative kernel =======================
__global__ __launch_bounds__(NTHR)
void fused_kernel(const int* __restrict__ tok,
                  const float* __restrict__ hidden,
                  const float* __restrict__ enc,
                  const float* __restrict__ emb,
                  const float* __restrict__ attn_W,
                  const float* __restrict__ attn_b,
                  const float* __restrict__ comb_W,
                  const float* __restrict__ comb_b,
                  const float* __restrict__ W_ih,
                  const float* __restrict__ W_hh,
                  const float* __restrict__ b_ih,
                  const float* __restrict__ b_hh,
                  const float* __restrict__ out_W,
                  const float* __restrict__ out_b,
                  float* __restrict__ out,
                  float* __restrict__ ws) {
    cg::grid_group grid = cg::this_grid();
    __shared__ float red[4];
    __shared__ float sAL[MAXLEN];
    __shared__ float wts[MAXLEN];
    __shared__ float cs[4][64];

    float* H1 = ws;          // [2048]
    float* AL = ws + 2048;   // [128]
    float* AA = ws + 2176;   // [2048]
    float* O  = ws + 4224;   // [2048]
    float* OH = ws + 6272;   // [2048]
    float* PE = ws + 8320;   // [NBLK] per-block exp partials

    const int bid = blockIdx.x, t = threadIdx.x;
    const int lane = t & 63, wid = t >> 6;
    const float4* xemb = (const float4*)(emb + (size_t)tok[0] * HID);
    const float4* xhid = (const float4*)hidden;

    auto block_sum = [&](float v) -> float {
        v = wave_sum(v);
        if (lane == 0) red[wid] = v;
        __syncthreads();
        float r = red[0] + red[1] + red[2] + red[3];
        __syncthreads();
        return r;
    };

    // ---- A: H1 = tanh(W_ih·emb[tok] + W_hh·hidden + b_ih + b_hh) ----
    for (int r = bid; r < HID; r += NBLK) {
        const float4* w1 = (const float4*)(W_ih + (size_t)r * HID);
        const float4* w2 = (const float4*)(W_hh + (size_t)r * HID);
        float p = dot4(w1[t], xemb[t]) + dot4(w1[t + 256], xemb[t + 256])
                + dot4(w2[t], xhid[t]) + dot4(w2[t + 256], xhid[t + 256]);
        p = block_sum(p);
        if (t == 0) H1[r] = tanhf(p + b_ih[r] + b_hh[r]);
    }
    grid.sync();

    // ---- B: AL = attn_W·[emb; H1] + attn_b (blocks 0..127) ----
    if (bid < MAXLEN) {
        const float4* w = (const float4*)(attn_W + (size_t)bid * 2 * HID);
        const float4* h1 = (const float4*)H1;
        float p = dot4(w[t], xemb[t]) + dot4(w[t + 256], xemb[t + 256])
                + dot4(w[t + 512], h1[t]) + dot4(w[t + 768], h1[t + 256]);
        p = block_sum(p);
        if (t == 0) AL[bid] = p + attn_b[bid];
    }
    grid.sync();

    // ---- C: AA = softmax(AL)·enc (blocks 0..31, 64 cols each) ----
    if (bid < HID / 64) {
        if (t < MAXLEN) sAL[t] = AL[t];
        __syncthreads();
        float m = sAL[0];
        for (int l = 1; l < MAXLEN; ++l) m = fmaxf(m, sAL[l]);
        float s = 0.f;
        for (int l = 0; l < MAXLEN; ++l) s += expf(sAL[l] - m);
        if (t < MAXLEN) wts[t] = expf(sAL[t] - m) / s;
        __syncthreads();
        const int j = bid * 64 + (t & 63);
        const int l0 = t >> 6;            // 0..3
        float acc = 0.f;
        #pragma unroll 8
        for (int l = l0; l < MAXLEN; l += 4) acc += wts[l] * enc[(size_t)l * HID + j];
        cs[l0][t & 63] = acc;
        __syncthreads();
        if (t < 64) AA[bid * 64 + t] = cs[0][t] + cs[1][t] + cs[2][t] + cs[3][t];
    }
    grid.sync();

    // ---- D: O = relu(comb_W·[emb; AA] + comb_b) ----
    for (int r = bid; r < HID; r += NBLK) {
        const float4* w = (const float4*)(comb_W + (size_t)r * 2 * HID);
        const float4* aa = (const float4*)AA;
        float p = dot4(w[t], xemb[t]) + dot4(w[t + 256], xemb[t + 256])
                + dot4(w[t + 512], aa[t]) + dot4(w[t + 768], aa[t + 256]);
        p = block_sum(p);
        if (t == 0) O[r] = fmaxf(p + comb_b[r], 0.f);
    }
    grid.sync();

    // ---- E: OH = tanh(W_ih·O + W_hh·H1 + b_ih + b_hh) ----
    for (int r = bid; r < HID; r += NBLK) {
        const float4* w1 = (const float4*)(W_ih + (size_t)r * HID);
        const float4* w2 = (const float4*)(W_hh + (size_t)r * HID);
        const float4* xo = (const float4*)O;
        const float4* xh = (const float4*)H1;
        float p = dot4(w1[t], xo[t]) + dot4(w1[t + 256], xo[t + 256])
                + dot4(w2[t], xh[t]) + dot4(w2[t + 256], xh[t + 256]);
        p = block_sum(p);
        if (t == 0) OH[r] = tanhf(p + b_ih[r] + b_hh[r]);
    }
    grid.sync();

    // ---- F: out = out_W·OH + out_b (wave/row, grid-strided); per-block exp partial ----
    {
        const float4* xv = (const float4*)OH;
        float eacc = 0.f;   // meaningful on lane 0 only
        for (int r = bid * 4 + wid; r < VOCAB; r += NBLK * 4) {
            const float4* w = (const float4*)(out_W + (size_t)r * HID);
            float p = 0.f;
            #pragma unroll
            for (int k = 0; k < 8; ++k) p += dot4(w[lane + k * 64], xv[lane + k * 64]);
            p = wave_sum(p);
            if (lane == 0) {
                p += out_b[r];
                out[r] = p;          // |logit| bounded (~41), exp() safe in f32
                eacc += expf(p);
            }
        }
        if (lane == 0) red[wid] = eacc;
        __syncthreads();
        if (t == 0) PE[bid] = red[0] + red[1] + red[2] + red[3];
        __syncthreads();
    }
    grid.sync();

    // ---- G: lg = log(sum PE) (redundant per block, deterministic); out -= lg ----
    {
        float v = PE[t] + PE[t + 256];           // NBLK == 512
        v = block_sum(v);
        float lg = logf(v);
        for (int i = bid * NTHR + t; i < VOCAB; i += NBLK * NTHR) out[i] -= lg;
    }
}

// ======================= fallback path (known-good R3) =======================
__device__ __forceinline__ float block_sum256_s(float v) {
    __shared__ float s[4];
    v = wave_sum(v);
    const int lane = threadIdx.x & 63, w = threadIdx.x >> 6;
    if (lane == 0) s[w] = v;
    __syncthreads();
    return s[0] + s[1] + s[2] + s[3];
}

__global__ __launch_bounds__(256)
void rnn_cell_kernel(const float* __restrict__ W1, const float* __restrict__ x1,
                     const int* __restrict__ tok,
                     const float* __restrict__ W2, const float* __restrict__ x2,
                     const float* __restrict__ b1, const float* __restrict__ b2,
                     float* __restrict__ out, float* __restrict__ zeroP) {
    const int r = blockIdx.x, t = threadIdx.x;
    if (zeroP && r == 0) zeroP[t] = 0.f;
    const float4* xa = (const float4*)(tok ? x1 + (size_t)tok[0] * HID : x1);
    const float4* xb = (const float4*)x2;
    const float4* w1 = (const float4*)(W1 + (size_t)r * HID);
    const float4* w2 = (const float4*)(W2 + (size_t)r * HID);
    float p = dot4(w1[t], xa[t]) + dot4(w1[t + 256], xa[t + 256])
            + dot4(w2[t], xb[t]) + dot4(w2[t + 256], xb[t + 256]);
    p = block_sum256_s(p);
    if (t == 0) out[r] = tanhf(p + b1[r] + b2[r]);
}

template<int ACT>
__global__ __launch_bounds__(256)
void concat_mv_kernel(const float* __restrict__ W,
                      const float* __restrict__ emb, const int* __restrict__ tok,
                      const float* __restrict__ xb, const float* __restrict__ b,
                      float* __restrict__ out) {
    const int r = blockIdx.x, t = threadIdx.x;
    const float4* xa = (const float4*)(emb + (size_t)tok[0] * HID);
    const float4* xv = (const float4*)xb;
    const float4* w  = (const float4*)(W + (size_t)r * 2 * HID);
    float p = dot4(w[t], xa[t]) + dot4(w[t + 256], xa[t + 256])
            + dot4(w[t + 512], xv[t]) + dot4(w[t + 768], xv[t + 256]);
    p = block_sum256_s(p);
    if (t == 0) {
        p += b[r];
        if (ACT == 2) p = fmaxf(p, 0.f);
        out[r] = p;
    }
}

__global__ __launch_bounds__(256)
void softmax_apply_kernel(const float* __restrict__ AL, const float* __restrict__ enc,
                          float* __restrict__ out) {
    __shared__ float sAL[MAXLEN];
    __shared__ float wts[MAXLEN];
    const int t = threadIdx.x;
    if (t < MAXLEN) sAL[t] = AL[t];
    __syncthreads();
    float m = sAL[0];
    for (int l = 1; l < MAXLEN; ++l) m = fmaxf(m, sAL[l]);
    float s = 0.f;
    for (int l = 0; l < MAXLEN; ++l) s += expf(sAL[l] - m);
    if (t < MAXLEN) wts[t] = expf(sAL[t] - m) / s;
    __syncthreads();
    const int j = blockIdx.x * blockDim.x + t;
    float acc = 0.f;
    #pragma unroll 4
    for (int l = 0; l < MAXLEN; ++l) acc += wts[l] * enc[(size_t)l * HID + j];
    out[j] = acc;
}

__global__ __launch_bounds__(256)
void bigmv_kernel(const float* __restrict__ W, const float* __restrict__ x,
                  const float* __restrict__ b, float* __restrict__ out,
                  float* __restrict__ partial) {
    const int r = blockIdx.x * 4 + (threadIdx.x >> 6);
    const int lane = threadIdx.x & 63;
    const float4* xv = (const float4*)x;
    const float4* w  = (const float4*)(W + (size_t)r * HID);
    float p = 0.f;
    #pragma unroll 8
    for (int i = lane; i < KQ; i += 64) p += dot4(w[i], xv[i]);
    p = wave_sum(p);
    if (lane == 0) {
        p += b[r];
        out[r] = p;
        atomicAdd(&partial[r & 255], expf(p));
    }
}

__global__ __launch_bounds__(256)
void finalize_kernel(const float* __restrict__ partial, float* __restrict__ out) {
    const int t = threadIdx.x;
    float lg = logf(block_sum256_s(partial[t]));
    const int i = blockIdx.x * 256 + t;
    out[i] -= lg;
}

extern "C" void kernel_launch(void* const* d_in, const int* in_sizes, int n_in,
                              void* d_out, int out_size, void* d_ws, size_t ws_size,
                              hipStream_t stream) {
    const int*   tok    = (const int*)  d_in[0];
    const float* hidden = (const float*)d_in[1];
    const float* enc    = (const float*)d_in[2];
    const float* emb    = (const float*)d_in[3];
    const float* attn_W = (const float*)d_in[4];
    const float* attn_b = (const float*)d_in[5];
    const float* comb_W = (const float*)d_in[6];
    const float* comb_b = (const float*)d_in[7];
    const float* W_ih   = (const float*)d_in[8];
    const float* W_hh   = (const float*)d_in[9];
    const float* b_ih   = (const float*)d_in[10];
    const float* b_hh   = (const float*)d_in[11];
    const float* out_W  = (const float*)d_in[12];
    const float* out_b  = (const float*)d_in[13];
    float* out = (float*)d_out;
    float* ws  = (float*)d_ws;

    void* args[] = { (void*)&tok, (void*)&hidden, (void*)&enc, (void*)&emb,
                     (void*)&attn_W, (void*)&attn_b, (void*)&comb_W, (void*)&comb_b,
                     (void*)&W_ih, (void*)&W_hh, (void*)&b_ih, (void*)&b_hh,
                     (void*)&out_W, (void*)&out_b, (void*)&out, (void*)&ws };
    hipError_t e = hipLaunchCooperativeKernel((const void*)fused_kernel,
                                              dim3(NBLK), dim3(NTHR), args, 0, stream);
    if (e != hipSuccess) {
        // -------- fallback: known-good multi-kernel chain --------
        float* H1 = ws;          // [2048]
        float* AL = ws + 2048;   // [128]
        float* AA = ws + 2176;   // [2048]
        float* O  = ws + 4224;   // [2048]
        float* OH = ws + 6272;   // [2048]
        float* P  = ws + 8320;   // [256]
        rnn_cell_kernel<<<HID, 256, 0, stream>>>(W_ih, emb, tok, W_hh, hidden, b_ih, b_hh, H1, P);
        concat_mv_kernel<0><<<MAXLEN, 256, 0, stream>>>(attn_W, emb, tok, H1, attn_b, AL);
        softmax_apply_kernel<<<HID / 256, 256, 0, stream>>>(AL, enc, AA);
        concat_mv_kernel<2><<<HID, 256, 0, stream>>>(comb_W, emb, tok, AA, comb_b, O);
        rnn_cell_kernel<<<HID, 256, 0, stream>>>(W_ih, O, nullptr, W_hh, H1, b_ih, b_hh, OH, nullptr);
        bigmv_kernel<<<VOCAB / 4, 256, 0, stream>>>(out_W, OH, out_b, out, P);
        finalize_kernel<<<VOCAB / 256, 256, 0, stream>>>(P, out);
    }
}

// Round 6
// 89.199 us; speedup vs baseline: 4.5789x; 4.5789x over previous
//
#include <hip/hip_runtime.h>
#include <math.h>

#define HID 2048
#define KQ (HID / 4)      // 512 float4 per HID-length row
#define MAXLEN 128
#define VOCAB 32000

__device__ __forceinline__ float wave_sum(float v) {
    #pragma unroll
    for (int m = 1; m < 64; m <<= 1) v += __shfl_xor(v, m, 64);
    return v;
}

__device__ __forceinline__ float dot4(float4 a, float4 b) {
    return a.x * b.x + a.y * b.y + a.z * b.z + a.w * b.w;
}

// block-level reduce for 256 threads (4 waves); same value on all threads
__device__ __forceinline__ float block_sum256(float v) {
    __shared__ float s[4];
    v = wave_sum(v);
    const int lane = threadIdx.x & 63, w = threadIdx.x >> 6;
    if (lane == 0) s[w] = v;
    __syncthreads();
    return s[0] + s[1] + s[2] + s[3];
}

// ---- RNN cell, block per row: out[r] = tanh(W1[r]·x1 + W2[r]·x2 + b1[r] + b2[r]) ----
// if tok != nullptr, x1 is an embedding table indexed by tok[0]
__global__ __launch_bounds__(256)
void rnn_cell_kernel(const float* __restrict__ W1, const float* __restrict__ x1,
                     const int* __restrict__ tok,
                     const float* __restrict__ W2, const float* __restrict__ x2,
                     const float* __restrict__ b1, const float* __restrict__ b2,
                     float* __restrict__ out) {
    const int r = blockIdx.x, t = threadIdx.x;
    const float4* xa = (const float4*)(tok ? x1 + (size_t)tok[0] * HID : x1);
    const float4* xb = (const float4*)x2;
    const float4* w1 = (const float4*)(W1 + (size_t)r * HID);
    const float4* w2 = (const float4*)(W2 + (size_t)r * HID);
    float p = dot4(w1[t], xa[t]) + dot4(w1[t + 256], xa[t + 256])
            + dot4(w2[t], xb[t]) + dot4(w2[t + 256], xb[t + 256]);
    p = block_sum256(p);
    if (t == 0) out[r] = tanhf(p + b1[r] + b2[r]);
}

// ---- concat matvec, block per row: out[r] = act(W[r,0:H]·emb_row + W[r,H:2H]·xb + b[r]) ----
template<int ACT>   // 0 = none, 2 = relu
__global__ __launch_bounds__(256)
void concat_mv_kernel(const float* __restrict__ W,
                      const float* __restrict__ emb, const int* __restrict__ tok,
                      const float* __restrict__ xb, const float* __restrict__ b,
                      float* __restrict__ out) {
    const int r = blockIdx.x, t = threadIdx.x;
    const float4* xa = (const float4*)(emb + (size_t)tok[0] * HID);
    const float4* xv = (const float4*)xb;
    const float4* w  = (const float4*)(W + (size_t)r * 2 * HID);
    float p = dot4(w[t], xa[t]) + dot4(w[t + 256], xa[t + 256])
            + dot4(w[t + 512], xv[t]) + dot4(w[t + 768], xv[t + 256]);
    p = block_sum256(p);
    if (t == 0) {
        p += b[r];
        if (ACT == 2) p = fmaxf(p, 0.f);
        out[r] = p;
    }
}

// ---- fused softmax(128) + apply, 32 blocks x 64 cols: AA[j] = sum_l sm(AL)[l]*enc[l][j] ----
__global__ __launch_bounds__(256)
void softmax_apply_kernel(const float* __restrict__ AL, const float* __restrict__ enc,
                          float* __restrict__ out) {
    __shared__ float sAL[MAXLEN];
    __shared__ float wts[MAXLEN];
    __shared__ float cs[4][64];
    const int t = threadIdx.x;
    if (t < MAXLEN) sAL[t] = AL[t];
    __syncthreads();
    // redundant per-thread softmax stats over 128 values (deterministic, cheap)
    float m = sAL[0];
    for (int l = 1; l < MAXLEN; ++l) m = fmaxf(m, sAL[l]);
    float s = 0.f;
    for (int l = 0; l < MAXLEN; ++l) s += expf(sAL[l] - m);
    if (t < MAXLEN) wts[t] = expf(sAL[t] - m) / s;
    __syncthreads();
    const int j  = blockIdx.x * 64 + (t & 63);
    const int l0 = t >> 6;                       // 0..3: L-split across waves
    float acc = 0.f;
    #pragma unroll 8
    for (int l = l0; l < MAXLEN; l += 4) acc += wts[l] * enc[(size_t)l * HID + j];
    cs[l0][t & 63] = acc;
    __syncthreads();
    if (t < 64) out[blockIdx.x * 64 + t] = cs[0][t] + cs[1][t] + cs[2][t] + cs[3][t];
}

// ---- big matvec, wave per row: out[r] = out_W[r]·x + b[r]; PE[bid] = block exp-sum ----
// |logit| <= ||W row||·||tanh vec|| ~ 41 -> exp() without max-subtraction is f32-safe.
__global__ __launch_bounds__(256)
void bigmv_kernel(const float* __restrict__ W, const float* __restrict__ x,
                  const float* __restrict__ b, float* __restrict__ out,
                  float* __restrict__ PE) {
    __shared__ float red[4];
    const int wid = threadIdx.x >> 6, lane = threadIdx.x & 63;
    const int r = blockIdx.x * 4 + wid;
    const float4* xv = (const float4*)x;
    const float4* w  = (const float4*)(W + (size_t)r * HID);
    float p = 0.f;
    #pragma unroll 8
    for (int i = lane; i < KQ; i += 64) p += dot4(w[i], xv[i]);
    p = wave_sum(p);
    if (lane == 0) {
        p += b[r];
        out[r] = p;
        red[wid] = expf(p);
    }
    __syncthreads();
    if (threadIdx.x == 0) PE[blockIdx.x] = red[0] + red[1] + red[2] + red[3];
}

// ---- lse apply: every block reduces PE[0..7999] identically (deterministic),
// then out[i] -= log(sum) for its 256-element chunk ----
__global__ __launch_bounds__(256)
void lse_apply_kernel(const float* __restrict__ PE, float* __restrict__ out) {
    const int t = threadIdx.x;
    float s = 0.f;
    for (int i = t; i < VOCAB / 4; i += 256) s += PE[i];   // 8000/256 ~ 31 reads, L2-hot
    const float lg = logf(block_sum256(s));
    out[blockIdx.x * 256 + t] -= lg;                       // 125*256 == 32000
}

extern "C" void kernel_launch(void* const* d_in, const int* in_sizes, int n_in,
                              void* d_out, int out_size, void* d_ws, size_t ws_size,
                              hipStream_t stream) {
    const int*   tok    = (const int*)  d_in[0];
    const float* hidden = (const float*)d_in[1];
    const float* enc    = (const float*)d_in[2];
    const float* emb    = (const float*)d_in[3];
    const float* attn_W = (const float*)d_in[4];
    const float* attn_b = (const float*)d_in[5];
    const float* comb_W = (const float*)d_in[6];
    const float* comb_b = (const float*)d_in[7];
    const float* W_ih   = (const float*)d_in[8];
    const float* W_hh   = (const float*)d_in[9];
    const float* b_ih   = (const float*)d_in[10];
    const float* b_hh   = (const float*)d_in[11];
    const float* out_W  = (const float*)d_in[12];
    const float* out_b  = (const float*)d_in[13];
    float* out = (float*)d_out;

    float* ws = (float*)d_ws;
    float* H1 = ws;          // [2048] hidden after rnn step 1
    float* AL = ws + 2048;   // [128]  attn logits
    float* AA = ws + 2176;   // [2048] attn applied
    float* O  = ws + 4224;   // [2048] combined + relu
    float* OH = ws + 6272;   // [2048] hidden after rnn step 2
    float* PE = ws + 8320;   // [8000] per-block exp partials

    // 1. H1 = tanh(W_ih·emb[tok] + W_hh·hidden + b_ih + b_hh)
    rnn_cell_kernel<<<HID, 256, 0, stream>>>(W_ih, emb, tok, W_hh, hidden, b_ih, b_hh, H1);
    // 2. AL = attn_W·[emb[tok]; H1] + attn_b
    concat_mv_kernel<0><<<MAXLEN, 256, 0, stream>>>(attn_W, emb, tok, H1, attn_b, AL);
    // 3. AA = softmax(AL)·enc
    softmax_apply_kernel<<<HID / 64, 256, 0, stream>>>(AL, enc, AA);
    // 4. O = relu(comb_W·[emb[tok]; AA] + comb_b)
    concat_mv_kernel<2><<<HID, 256, 0, stream>>>(comb_W, emb, tok, AA, comb_b, O);
    // 5. OH = tanh(W_ih·O + W_hh·H1 + b_ih + b_hh)
    rnn_cell_kernel<<<HID, 256, 0, stream>>>(W_ih, O, nullptr, W_hh, H1, b_ih, b_hh, OH);
    // 6. out = out_W·OH + out_b; PE[bid] = per-block sum of exp(logit)
    bigmv_kernel<<<VOCAB / 4, 256, 0, stream>>>(out_W, OH, out_b, out, PE);
    // 7. out[i] -= log(sum PE)
    lse_apply_kernel<<<VOCAB / 256, 256, 0, stream>>>(PE, out);
}

// Round 7
// 89.083 us; speedup vs baseline: 4.5849x; 1.0013x over previous
//
#include <hip/hip_runtime.h>
#include <math.h>

#define HID 2048
#define KQ (HID / 4)      // 512 float4 per HID-length row
#define MAXLEN 128
#define VOCAB 32000

__device__ __forceinline__ float wave_sum(float v) {
    #pragma unroll
    for (int m = 1; m < 64; m <<= 1) v += __shfl_xor(v, m, 64);
    return v;
}

__device__ __forceinline__ float dot4(float4 a, float4 b) {
    return a.x * b.x + a.y * b.y + a.z * b.z + a.w * b.w;
}

// block-level reduce for 256 threads (4 waves); same value on all threads
__device__ __forceinline__ float block_sum256(float v) {
    __shared__ float s[4];
    v = wave_sum(v);
    const int lane = threadIdx.x & 63, w = threadIdx.x >> 6;
    if (lane == 0) s[w] = v;
    __syncthreads();
    return s[0] + s[1] + s[2] + s[3];
}

// 2048-wide dot of row `w` (float4*) against vector `x` (float4*), 256 threads
__device__ __forceinline__ float row_dot2048(const float4* __restrict__ w,
                                             const float4* __restrict__ x) {
    const int t = threadIdx.x;
    return dot4(w[t], x[t]) + dot4(w[t + 256], x[t + 256]);
}

// ---- K1: blocks 0..2047 -> H1 rows; blocks 2048..2175 -> ALe rows ----
__global__ __launch_bounds__(256)
void k1_rnn1_attnleft(const float* __restrict__ W_ih, const float* __restrict__ W_hh,
                      const float* __restrict__ emb, const int* __restrict__ tok,
                      const float* __restrict__ hidden,
                      const float* __restrict__ b_ih, const float* __restrict__ b_hh,
                      const float* __restrict__ attn_W, const float* __restrict__ attn_b,
                      float* __restrict__ H1, float* __restrict__ ALe) {
    const float4* xemb = (const float4*)(emb + (size_t)tok[0] * HID);
    const int bid = blockIdx.x, t = threadIdx.x;
    if (bid < HID) {
        const float4* w1 = (const float4*)(W_ih + (size_t)bid * HID);
        const float4* w2 = (const float4*)(W_hh + (size_t)bid * HID);
        float p = row_dot2048(w1, xemb) + row_dot2048(w2, (const float4*)hidden);
        p = block_sum256(p);
        if (t == 0) H1[bid] = tanhf(p + b_ih[bid] + b_hh[bid]);
    } else {
        const int l = bid - HID;   // 0..127
        const float4* w = (const float4*)(attn_W + (size_t)l * 2 * HID);  // left half
        float p = block_sum256(row_dot2048(w, xemb));
        if (t == 0) ALe[l] = p + attn_b[l];
    }
}

// ---- K2: blocks 0..127 -> AL = ALe + attn_W_right·H1; blocks 128..2175 -> Oe ----
__global__ __launch_bounds__(256)
void k2_attnright_combleft(const float* __restrict__ attn_W,
                           const float* __restrict__ comb_W, const float* __restrict__ comb_b,
                           const float* __restrict__ emb, const int* __restrict__ tok,
                           const float* __restrict__ H1, const float* __restrict__ ALe,
                           float* __restrict__ AL, float* __restrict__ Oe) {
    const int bid = blockIdx.x, t = threadIdx.x;
    if (bid < MAXLEN) {
        const float4* w = (const float4*)(attn_W + (size_t)bid * 2 * HID + HID); // right half
        float p = block_sum256(row_dot2048(w, (const float4*)H1));
        if (t == 0) AL[bid] = ALe[bid] + p;
    } else {
        const int r = bid - MAXLEN;   // 0..2047
        const float4* xemb = (const float4*)(emb + (size_t)tok[0] * HID);
        const float4* w = (const float4*)(comb_W + (size_t)r * 2 * HID);         // left half
        float p = block_sum256(row_dot2048(w, xemb));
        if (t == 0) Oe[r] = p + comb_b[r];
    }
}

// ---- K3: AA = softmax(AL)·enc, 32 blocks x 64 cols ----
__global__ __launch_bounds__(256)
void k3_softmax_apply(const float* __restrict__ AL, const float* __restrict__ enc,
                      float* __restrict__ AA) {
    __shared__ float sAL[MAXLEN];
    __shared__ float wts[MAXLEN];
    __shared__ float cs[4][64];
    const int t = threadIdx.x;
    if (t < MAXLEN) sAL[t] = AL[t];
    __syncthreads();
    float m = sAL[0];
    for (int l = 1; l < MAXLEN; ++l) m = fmaxf(m, sAL[l]);
    float s = 0.f;
    for (int l = 0; l < MAXLEN; ++l) s += expf(sAL[l] - m);
    if (t < MAXLEN) wts[t] = expf(sAL[t] - m) / s;
    __syncthreads();
    const int j  = blockIdx.x * 64 + (t & 63);
    const int l0 = t >> 6;
    float acc = 0.f;
    #pragma unroll 8
    for (int l = l0; l < MAXLEN; l += 4) acc += wts[l] * enc[(size_t)l * HID + j];
    cs[l0][t & 63] = acc;
    __syncthreads();
    if (t < 64) AA[blockIdx.x * 64 + t] = cs[0][t] + cs[1][t] + cs[2][t] + cs[3][t];
}

// ---- K4: O = relu(Oe + comb_W_right·AA) ----
__global__ __launch_bounds__(256)
void k4_comb_right(const float* __restrict__ comb_W, const float* __restrict__ AA,
                   const float* __restrict__ Oe, float* __restrict__ O) {
    const int r = blockIdx.x, t = threadIdx.x;
    const float4* w = (const float4*)(comb_W + (size_t)r * 2 * HID + HID);  // right half
    float p = block_sum256(row_dot2048(w, (const float4*)AA));
    if (t == 0) O[r] = fmaxf(Oe[r] + p, 0.f);
}

// ---- K5: OH = tanh(W_ih·O + W_hh·H1 + b_ih + b_hh) (weights L3-hot from K1) ----
__global__ __launch_bounds__(256)
void k5_rnn2(const float* __restrict__ W_ih, const float* __restrict__ W_hh,
             const float* __restrict__ O, const float* __restrict__ H1,
             const float* __restrict__ b_ih, const float* __restrict__ b_hh,
             float* __restrict__ OH) {
    const int r = blockIdx.x, t = threadIdx.x;
    const float4* w1 = (const float4*)(W_ih + (size_t)r * HID);
    const float4* w2 = (const float4*)(W_hh + (size_t)r * HID);
    float p = row_dot2048(w1, (const float4*)O) + row_dot2048(w2, (const float4*)H1);
    p = block_sum256(p);
    if (t == 0) OH[r] = tanhf(p + b_ih[r] + b_hh[r]);
}

// ---- K6: big matvec, wave per row; PE[bid] = block sum of exp(logit) ----
// |logit| <= ||W row||·||OH|| ~ 41 -> exp() without max-subtraction is f32-safe.
__global__ __launch_bounds__(256)
void k6_bigmv(const float* __restrict__ W, const float* __restrict__ x,
              const float* __restrict__ b, float* __restrict__ out,
              float* __restrict__ PE) {
    __shared__ float red[4];
    const int wid = threadIdx.x >> 6, lane = threadIdx.x & 63;
    const int r = blockIdx.x * 4 + wid;
    const float4* xv = (const float4*)x;
    const float4* w  = (const float4*)(W + (size_t)r * HID);
    float p0 = 0.f, p1 = 0.f;
    #pragma unroll
    for (int k = 0; k < 8; k += 2) {
        p0 += dot4(w[lane + k * 64], xv[lane + k * 64]);
        p1 += dot4(w[lane + (k + 1) * 64], xv[lane + (k + 1) * 64]);
    }
    float p = wave_sum(p0 + p1);
    if (lane == 0) {
        p += b[r];
        out[r] = p;
        red[wid] = expf(p);
    }
    __syncthreads();
    if (threadIdx.x == 0) PE[blockIdx.x] = red[0] + red[1] + red[2] + red[3];
}

// ---- K7: every block reduces PE identically (deterministic); out -= log(sum) ----
__global__ __launch_bounds__(256)
void k7_lse_apply(const float* __restrict__ PE, float* __restrict__ out) {
    const int t = threadIdx.x;
    float s = 0.f;
    for (int i = t; i < VOCAB / 4; i += 256) s += PE[i];
    const float lg = logf(block_sum256(s));
    out[blockIdx.x * 256 + t] -= lg;    // 125 * 256 == 32000
}

extern "C" void kernel_launch(void* const* d_in, const int* in_sizes, int n_in,
                              void* d_out, int out_size, void* d_ws, size_t ws_size,
                              hipStream_t stream) {
    const int*   tok    = (const int*)  d_in[0];
    const float* hidden = (const float*)d_in[1];
    const float* enc    = (const float*)d_in[2];
    const float* emb    = (const float*)d_in[3];
    const float* attn_W = (const float*)d_in[4];
    const float* attn_b = (const float*)d_in[5];
    const float* comb_W = (const float*)d_in[6];
    const float* comb_b = (const float*)d_in[7];
    const float* W_ih   = (const float*)d_in[8];
    const float* W_hh   = (const float*)d_in[9];
    const float* b_ih   = (const float*)d_in[10];
    const float* b_hh   = (const float*)d_in[11];
    const float* out_W  = (const float*)d_in[12];
    const float* out_b  = (const float*)d_in[13];
    float* out = (float*)d_out;

    float* ws  = (float*)d_ws;
    float* H1  = ws;          // [2048]
    float* ALe = ws + 2048;   // [128]  attn-left partial (+bias)
    float* AL  = ws + 2176;   // [128]  full attn logits
    float* AA  = ws + 2304;   // [2048] attn applied
    float* Oe  = ws + 4352;   // [2048] comb-left partial (+bias)
    float* O   = ws + 6400;   // [2048] combined + relu
    float* OH  = ws + 8448;   // [2048] hidden after rnn2
    float* PE  = ws + 10496;  // [8000] per-block exp partials

    // K1: H1 + ALe            (33.6 MB + 1 MB)
    k1_rnn1_attnleft<<<HID + MAXLEN, 256, 0, stream>>>(W_ih, W_hh, emb, tok, hidden,
                                                       b_ih, b_hh, attn_W, attn_b, H1, ALe);
    // K2: AL + Oe             (1 MB + 16.8 MB)
    k2_attnright_combleft<<<MAXLEN + HID, 256, 0, stream>>>(attn_W, comb_W, comb_b,
                                                            emb, tok, H1, ALe, AL, Oe);
    // K3: AA = softmax(AL)·enc (1 MB)
    k3_softmax_apply<<<HID / 64, 256, 0, stream>>>(AL, enc, AA);
    // K4: O = relu(Oe + comb_right·AA)  (16.8 MB)
    k4_comb_right<<<HID, 256, 0, stream>>>(comb_W, AA, Oe, O);
    // K5: OH = tanh(W_ih·O + W_hh·H1 + b)  (33.6 MB, L3-hot)
    k5_rnn2<<<HID, 256, 0, stream>>>(W_ih, W_hh, O, H1, b_ih, b_hh, OH);
    // K6: logits + per-block exp partials  (262 MB)
    k6_bigmv<<<VOCAB / 4, 256, 0, stream>>>(out_W, OH, out_b, out, PE);
    // K7: out -= log(sum(exp))
    k7_lse_apply<<<VOCAB / 256, 256, 0, stream>>>(PE, out);
}

// Round 8
// 85.971 us; speedup vs baseline: 4.7509x; 1.0362x over previous
//
#include <hip/hip_runtime.h>
#include <math.h>

#define HID 2048
#define MAXLEN 128
#define VOCAB 32000

__device__ __forceinline__ float wave_sum(float v) {
    #pragma unroll
    for (int m = 1; m < 64; m <<= 1) v += __shfl_xor(v, m, 64);
    return v;
}

__device__ __forceinline__ float dot4(float4 a, float4 b) {
    return a.x * b.x + a.y * b.y + a.z * b.z + a.w * b.w;
}

// block-level reduce for 256 threads (4 waves); same value on all threads
__device__ __forceinline__ float block_sum256(float v) {
    __shared__ float s[4];
    v = wave_sum(v);
    const int lane = threadIdx.x & 63, w = threadIdx.x >> 6;
    if (lane == 0) s[w] = v;
    __syncthreads();
    return s[0] + s[1] + s[2] + s[3];
}

// 2048-wide dot of row `w` against vector `x` (both float4*), 256 threads
__device__ __forceinline__ float row_dot2048(const float4* __restrict__ w,
                                             const float4* __restrict__ x) {
    const int t = threadIdx.x;
    return dot4(w[t], x[t]) + dot4(w[t + 256], x[t + 256]);
}

// ---- K1: blocks [0,2048) H1 rows; [2048,2176) ALe rows; [2176,4224) Oe rows ----
__global__ __launch_bounds__(256)
void k1_fused_left(const float* __restrict__ W_ih, const float* __restrict__ W_hh,
                   const float* __restrict__ emb, const int* __restrict__ tok,
                   const float* __restrict__ hidden,
                   const float* __restrict__ b_ih, const float* __restrict__ b_hh,
                   const float* __restrict__ attn_W, const float* __restrict__ attn_b,
                   const float* __restrict__ comb_W, const float* __restrict__ comb_b,
                   float* __restrict__ H1, float* __restrict__ ALe,
                   float* __restrict__ Oe) {
    const float4* xemb = (const float4*)(emb + (size_t)tok[0] * HID);
    const int bid = blockIdx.x, t = threadIdx.x;
    if (bid < HID) {                       // H1 row
        const float4* w1 = (const float4*)(W_ih + (size_t)bid * HID);
        const float4* w2 = (const float4*)(W_hh + (size_t)bid * HID);
        float p = row_dot2048(w1, xemb) + row_dot2048(w2, (const float4*)hidden);
        p = block_sum256(p);
        if (t == 0) H1[bid] = tanhf(p + b_ih[bid] + b_hh[bid]);
    } else if (bid < HID + MAXLEN) {       // attn-left row
        const int l = bid - HID;
        const float4* w = (const float4*)(attn_W + (size_t)l * 2 * HID);
        float p = block_sum256(row_dot2048(w, xemb));
        if (t == 0) ALe[l] = p + attn_b[l];
    } else {                               // comb-left row
        const int r = bid - HID - MAXLEN;
        const float4* w = (const float4*)(comb_W + (size_t)r * 2 * HID);
        float p = block_sum256(row_dot2048(w, xemb));
        if (t == 0) Oe[r] = p + comb_b[r];
    }
}

// ---- K2: AL[l] = ALe[l] + attn_W_right[l]·H1 (128 blocks, ~1 MB, L3-hot) ----
__global__ __launch_bounds__(256)
void k2_attn_right(const float* __restrict__ attn_W, const float* __restrict__ H1,
                   const float* __restrict__ ALe, float* __restrict__ AL) {
    const int l = blockIdx.x, t = threadIdx.x;
    const float4* w = (const float4*)(attn_W + (size_t)l * 2 * HID + HID);
    float p = block_sum256(row_dot2048(w, (const float4*)H1));
    if (t == 0) AL[l] = ALe[l] + p;
}

// ---- K3: AA = softmax(AL)·enc, 32 blocks x 64 cols ----
__global__ __launch_bounds__(256)
void k3_softmax_apply(const float* __restrict__ AL, const float* __restrict__ enc,
                      float* __restrict__ AA) {
    __shared__ float sAL[MAXLEN];
    __shared__ float wts[MAXLEN];
    __shared__ float cs[4][64];
    const int t = threadIdx.x;
    if (t < MAXLEN) sAL[t] = AL[t];
    __syncthreads();
    float m = sAL[0];
    for (int l = 1; l < MAXLEN; ++l) m = fmaxf(m, sAL[l]);
    float s = 0.f;
    for (int l = 0; l < MAXLEN; ++l) s += expf(sAL[l] - m);
    if (t < MAXLEN) wts[t] = expf(sAL[t] - m) / s;
    __syncthreads();
    const int j  = blockIdx.x * 64 + (t & 63);
    const int l0 = t >> 6;
    float acc = 0.f;
    #pragma unroll 8
    for (int l = l0; l < MAXLEN; l += 4) acc += wts[l] * enc[(size_t)l * HID + j];
    cs[l0][t & 63] = acc;
    __syncthreads();
    if (t < 64) AA[blockIdx.x * 64 + t] = cs[0][t] + cs[1][t] + cs[2][t] + cs[3][t];
}

// ---- K4: O = relu(Oe + comb_W_right·AA) ----
__global__ __launch_bounds__(256)
void k4_comb_right(const float* __restrict__ comb_W, const float* __restrict__ AA,
                   const float* __restrict__ Oe, float* __restrict__ O) {
    const int r = blockIdx.x, t = threadIdx.x;
    const float4* w = (const float4*)(comb_W + (size_t)r * 2 * HID + HID);
    float p = block_sum256(row_dot2048(w, (const float4*)AA));
    if (t == 0) O[r] = fmaxf(Oe[r] + p, 0.f);
}

// ---- K5: OH = tanh(W_ih·O + W_hh·H1 + b_ih + b_hh) ----
__global__ __launch_bounds__(256)
void k5_rnn2(const float* __restrict__ W_ih, const float* __restrict__ W_hh,
             const float* __restrict__ O, const float* __restrict__ H1,
             const float* __restrict__ b_ih, const float* __restrict__ b_hh,
             float* __restrict__ OH) {
    const int r = blockIdx.x, t = threadIdx.x;
    const float4* w1 = (const float4*)(W_ih + (size_t)r * HID);
    const float4* w2 = (const float4*)(W_hh + (size_t)r * HID);
    float p = row_dot2048(w1, (const float4*)O) + row_dot2048(w2, (const float4*)H1);
    p = block_sum256(p);
    if (t == 0) OH[r] = tanhf(p + b_ih[r] + b_hh[r]);
}

// ---- K6: big matvec, 2 rows per wave (16 w-loads in flight, shared x chunk) ----
// |logit| <= ||W row||·||OH|| ~ 41 -> exp() without max-subtraction is f32-safe.
__global__ __launch_bounds__(256)
void k6_bigmv(const float* __restrict__ W, const float* __restrict__ x,
              const float* __restrict__ b, float* __restrict__ out,
              float* __restrict__ PE) {
    __shared__ float red[4];
    const int wid = threadIdx.x >> 6, lane = threadIdx.x & 63;
    const int r0 = blockIdx.x * 8 + wid * 2;            // rows r0, r0+1
    const float4* xv = (const float4*)x;
    const float4* w0 = (const float4*)(W + (size_t)r0 * HID);
    const float4* w1 = (const float4*)(W + (size_t)(r0 + 1) * HID);
    float a0 = 0.f, a1 = 0.f;
    #pragma unroll
    for (int k = 0; k < 8; ++k) {
        const float4 xc = xv[lane + k * 64];
        a0 += dot4(w0[lane + k * 64], xc);
        a1 += dot4(w1[lane + k * 64], xc);
    }
    a0 = wave_sum(a0);
    a1 = wave_sum(a1);
    if (lane == 0) {
        a0 += b[r0];
        a1 += b[r0 + 1];
        out[r0] = a0;
        out[r0 + 1] = a1;
        red[wid] = expf(a0) + expf(a1);
    }
    __syncthreads();
    if (threadIdx.x == 0) PE[blockIdx.x] = red[0] + red[1] + red[2] + red[3];
}

// ---- K7: every block reduces PE identically (deterministic); out -= log(sum) ----
__global__ __launch_bounds__(256)
void k7_lse_apply(const float* __restrict__ PE, float* __restrict__ out) {
    const int t = threadIdx.x;
    float s = 0.f;
    for (int i = t; i < VOCAB / 8; i += 256) s += PE[i];   // 4000 partials
    const float lg = logf(block_sum256(s));
    out[blockIdx.x * 256 + t] -= lg;                       // 125 * 256 == 32000
}

extern "C" void kernel_launch(void* const* d_in, const int* in_sizes, int n_in,
                              void* d_out, int out_size, void* d_ws, size_t ws_size,
                              hipStream_t stream) {
    const int*   tok    = (const int*)  d_in[0];
    const float* hidden = (const float*)d_in[1];
    const float* enc    = (const float*)d_in[2];
    const float* emb    = (const float*)d_in[3];
    const float* attn_W = (const float*)d_in[4];
    const float* attn_b = (const float*)d_in[5];
    const float* comb_W = (const float*)d_in[6];
    const float* comb_b = (const float*)d_in[7];
    const float* W_ih   = (const float*)d_in[8];
    const float* W_hh   = (const float*)d_in[9];
    const float* b_ih   = (const float*)d_in[10];
    const float* b_hh   = (const float*)d_in[11];
    const float* out_W  = (const float*)d_in[12];
    const float* out_b  = (const float*)d_in[13];
    float* out = (float*)d_out;

    float* ws  = (float*)d_ws;
    float* H1  = ws;          // [2048]
    float* ALe = ws + 2048;   // [128]
    float* AL  = ws + 2176;   // [128]
    float* AA  = ws + 2304;   // [2048]
    float* Oe  = ws + 4352;   // [2048]
    float* O   = ws + 6400;   // [2048]
    float* OH  = ws + 8448;   // [2048]
    float* PE  = ws + 10496;  // [4000]

    // K1: H1 + ALe + Oe   (52.4 MB, machine-filling)
    k1_fused_left<<<HID + MAXLEN + HID, 256, 0, stream>>>(W_ih, W_hh, emb, tok, hidden,
                                                          b_ih, b_hh, attn_W, attn_b,
                                                          comb_W, comb_b, H1, ALe, Oe);
    // K2: AL = ALe + attn_right·H1   (1 MB, L3-hot)
    k2_attn_right<<<MAXLEN, 256, 0, stream>>>(attn_W, H1, ALe, AL);
    // K3: AA = softmax(AL)·enc       (1 MB)
    k3_softmax_apply<<<HID / 64, 256, 0, stream>>>(AL, enc, AA);
    // K4: O = relu(Oe + comb_right·AA)  (16.8 MB)
    k4_comb_right<<<HID, 256, 0, stream>>>(comb_W, AA, Oe, O);
    // K5: OH = tanh(W_ih·O + W_hh·H1 + b)  (33.6 MB, L3-warm)
    k5_rnn2<<<HID, 256, 0, stream>>>(W_ih, W_hh, O, H1, b_ih, b_hh, OH);
    // K6: logits + per-block exp partials  (262 MB, 2 rows/wave)
    k6_bigmv<<<VOCAB / 8, 256, 0, stream>>>(out_W, OH, out_b, out, PE);
    // K7: out -= log(sum(exp))
    k7_lse_apply<<<VOCAB / 256, 256, 0, stream>>>(PE, out);
}